// Round 2
// baseline (1141.753 us; speedup 1.0000x reference)
//
#include <hip/hip_runtime.h>
#include <stdint.h>
#include <stddef.h>

// Narrow MHA: B=8, S=1024, D=512 (per head), H=8.
// fp16 MFMA GEMMs (16x16x32_f16), fp32 softmax, fp32 outputs (out, attn).
// R6: k_attn = 16-wave (1024-thr) TQ=64 block, acc[4][4]/lane, double-buffered
// K staging (issue-ahead), XCD-swizzled (b,h) placement for K/V L2 locality.
// LDS: phase1 2x64KB Ks dbuf; phase2 Pa 64x1024 chunked (147.7KB); red 4KB.
typedef _Float16 h16;
typedef __attribute__((ext_vector_type(4))) _Float16 h16x4;
typedef __attribute__((ext_vector_type(8))) _Float16 h16x8;
typedef __attribute__((ext_vector_type(4))) float f32x4;

#define MFMA16(a, b, c) __builtin_amdgcn_mfma_f32_16x16x32_f16((a), (b), (c), 0, 0, 0)

#define NB 8
#define SEQ 1024
#define DEP 512
#define NH 8
#define HD 4096  /* NH*DEP */
#define BS 8192  /* NB*SEQ */

static __device__ __forceinline__ void gload_lds16(const void* g, void* l) {
  __builtin_amdgcn_global_load_lds((__attribute__((address_space(1))) void*)(g),
                                   (__attribute__((address_space(3))) void*)(l),
                                   16, 0, 0);
}

static __device__ __forceinline__ h16 f2h(float f) { return (h16)f; }

// ---------------- fused fp32 -> fp16 for q,k,v ----------------
__global__ __launch_bounds__(256) void k_conv3(const float* __restrict__ q,
                                               const float* __restrict__ k,
                                               const float* __restrict__ v,
                                               h16* __restrict__ xq, h16* __restrict__ xk,
                                               h16* __restrict__ xv) {
  int z = blockIdx.y;
  const float* in = z == 0 ? q : (z == 1 ? k : v);
  h16* out = z == 0 ? xq : (z == 1 ? xk : xv);
  int i = blockIdx.x * 256 + threadIdx.x;
  float4 f = ((const float4*)in)[i];
  h16x4 o = { f2h(f.x), f2h(f.y), f2h(f.z), f2h(f.w) };
  ((h16x4*)out)[i] = o;
}

// ---------------- mask (0/1 fp32, B*S*S floats) -> bitmask (262144 uint32) ----------------
__global__ __launch_bounds__(256) void k_maskbits(const float* __restrict__ mask,
                                                  uint32_t* __restrict__ bits) {
  int g = blockIdx.x * 256 + threadIdx.x;  // 262,144 threads, 32 floats each
  const float4* mp = (const float4*)mask + (size_t)g * 8;
  uint32_t w = 0;
#pragma unroll
  for (int u = 0; u < 8; ++u) {
    float4 f = mp[u];
    w |= (f.x != 0.f ? 1u : 0u) << (u * 4);
    w |= (f.y != 0.f ? 1u : 0u) << (u * 4 + 1);
    w |= (f.z != 0.f ? 1u : 0u) << (u * 4 + 2);
    w |= (f.w != 0.f ? 1u : 0u) << (u * 4 + 3);
  }
  bits[g] = w;
}

// ---------------- transpose + convert: in (R x C) fp32 -> out (C x R) fp16 ----------------
__global__ __launch_bounds__(256) void k_transpose(const float* __restrict__ in,
                                                   h16* __restrict__ out, int R, int C) {
  __shared__ float t[32][33];
  int c0 = blockIdx.x * 32, r0 = blockIdx.y * 32;
  int tx = threadIdx.x & 31, ty = threadIdx.x >> 5;
  for (int p = 0; p < 4; ++p)
    t[ty + p * 8][tx] = in[(size_t)(r0 + ty + p * 8) * C + c0 + tx];
  __syncthreads();
  for (int p = 0; p < 4; ++p)
    out[(size_t)(c0 + ty + p * 8) * R + r0 + tx] = f2h(t[tx][ty + p * 8]);
}

__global__ __launch_bounds__(256) void k_transpose3(const float* __restrict__ wq,
                                                    const float* __restrict__ wk,
                                                    const float* __restrict__ wv,
                                                    h16* __restrict__ oq, h16* __restrict__ ok,
                                                    h16* __restrict__ ov) {
  __shared__ float t[32][33];
  int z = blockIdx.z;
  const float* in = z == 0 ? wq : (z == 1 ? wk : wv);
  h16* out = z == 0 ? oq : (z == 1 ? ok : ov);
  const int R = 512, C = 4096;
  int c0 = blockIdx.x * 32, r0 = blockIdx.y * 32;
  int tx = threadIdx.x & 31, ty = threadIdx.x >> 5;
  for (int p = 0; p < 4; ++p)
    t[ty + p * 8][tx] = in[(size_t)(r0 + ty + p * 8) * C + c0 + tx];
  __syncthreads();
  for (int p = 0; p < 4; ++p)
    out[(size_t)(c0 + ty + p * 8) * R + r0 + tx] = f2h(t[tx][ty + p * 8]);
}

// ---------------- merged QKV projection GEMM ----------------
__global__ __launch_bounds__(256) void k_gemm_qkv(
    const h16* __restrict__ xq, const h16* __restrict__ xk, const h16* __restrict__ xv,
    const h16* __restrict__ WqT, const h16* __restrict__ WkT, const h16* __restrict__ WvT,
    const float* __restrict__ bq, const float* __restrict__ bk, const float* __restrict__ bv,
    h16* __restrict__ Qh, h16* __restrict__ Kh, h16* __restrict__ Vt) {
  __shared__ __align__(16) h16 As[128 * 64];
  __shared__ __align__(16) h16 Bs[128 * 64];
  const int z = blockIdx.z;
  const h16* A = z == 0 ? xq : (z == 1 ? xk : xv);
  const h16* Bm = z == 0 ? WqT : (z == 1 ? WkT : WvT);
  const float* bias = z == 0 ? bq : (z == 1 ? bk : bv);
  const int K = 512;
  const int tid = threadIdx.x, lane = tid & 63, wave = tid >> 6;
  const int wm = (wave >> 1) * 64, wn = (wave & 1) * 64;
  const int m0 = blockIdx.y * 128;
  const int n0 = blockIdx.x * 128;

  f32x4 acc[4][4];
  for (int i = 0; i < 4; ++i)
    for (int j = 0; j < 4; ++j) acc[i][j] = (f32x4)0.0f;

  const int lrow = lane >> 3, lcol = (lane & 7) * 8;
  const int fr = lane & 15, qd = lane >> 4;

  for (int k0 = 0; k0 < K; k0 += 64) {
    __syncthreads();
    for (int i = 0; i < 4; ++i) {
      int g = wave * 4 + i;
      int row = g * 8 + lrow;
      gload_lds16(A + (size_t)(m0 + row) * K + k0 + lcol, As + g * 512);
      gload_lds16(Bm + (size_t)(n0 + row) * K + k0 + lcol, Bs + g * 512);
    }
    __syncthreads();
    for (int kk = 0; kk < 64; kk += 32) {
      h16x8 af[4], bf[4];
      for (int i = 0; i < 4; ++i)
        af[i] = *(const h16x8*)(As + (wm + i * 16 + fr) * 64 + kk + qd * 8);
      for (int j = 0; j < 4; ++j)
        bf[j] = *(const h16x8*)(Bs + (wn + j * 16 + fr) * 64 + kk + qd * 8);
      for (int i = 0; i < 4; ++i)
        for (int j = 0; j < 4; ++j) acc[i][j] = MFMA16(af[i], bf[j], acc[i][j]);
    }
  }

  h16* Cnat = z == 0 ? Qh : Kh;
  for (int i = 0; i < 4; ++i)
    for (int j = 0; j < 4; ++j) {
      int mbase = m0 + wm + i * 16 + qd * 4;
      int ncol = n0 + wn + j * 16 + fr;
      float bv2 = bias[ncol];
      if (z < 2) {
        for (int r = 0; r < 4; ++r)
          Cnat[(size_t)(mbase + r) * HD + ncol] = f2h(acc[i][j][r] + bv2);
      } else {
        int bb = mbase >> 10, ss = mbase & 1023;
        int hh = ncol >> 9, dd = ncol & 511;
        size_t addr = ((size_t)((bb * NH + hh) * DEP + dd)) * SEQ + ss;
        h16x4 pk = { f2h(acc[i][j][0] + bv2), f2h(acc[i][j][1] + bv2),
                     f2h(acc[i][j][2] + bv2), f2h(acc[i][j][3] + bv2) };
        *(h16x4*)(Vt + addr) = pk;
      }
    }
}

// ---------------- NT GEMM (out-projection): fp32 out ----------------
template <int OUT_MODE>
__global__ __launch_bounds__(256) void k_gemm_nt(const h16* __restrict__ A,
                                                 const h16* __restrict__ Bm,
                                                 const float* __restrict__ bias,
                                                 void* __restrict__ Cout,
                                                 int M, int N, int K, int ldc) {
  __shared__ __align__(16) h16 As[128 * 64];
  __shared__ __align__(16) h16 Bs[128 * 64];
  const int tid = threadIdx.x, lane = tid & 63, wave = tid >> 6;
  const int wm = (wave >> 1) * 64, wn = (wave & 1) * 64;
  const int m0 = blockIdx.y * 128;
  const int n0 = blockIdx.x * 128;

  f32x4 acc[4][4];
  for (int i = 0; i < 4; ++i)
    for (int j = 0; j < 4; ++j) acc[i][j] = (f32x4)0.0f;

  const int lrow = lane >> 3, lcol = (lane & 7) * 8;
  const int fr = lane & 15, qd = lane >> 4;

  for (int k0 = 0; k0 < K; k0 += 64) {
    __syncthreads();
    for (int i = 0; i < 4; ++i) {
      int g = wave * 4 + i;
      int row = g * 8 + lrow;
      gload_lds16(A + (size_t)(m0 + row) * K + k0 + lcol, As + g * 512);
      gload_lds16(Bm + (size_t)(n0 + row) * K + k0 + lcol, Bs + g * 512);
    }
    __syncthreads();
    for (int kk = 0; kk < 64; kk += 32) {
      h16x8 af[4], bf[4];
      for (int i = 0; i < 4; ++i)
        af[i] = *(const h16x8*)(As + (wm + i * 16 + fr) * 64 + kk + qd * 8);
      for (int j = 0; j < 4; ++j)
        bf[j] = *(const h16x8*)(Bs + (wn + j * 16 + fr) * 64 + kk + qd * 8);
      for (int i = 0; i < 4; ++i)
        for (int j = 0; j < 4; ++j) acc[i][j] = MFMA16(af[i], bf[j], acc[i][j]);
    }
  }

  for (int i = 0; i < 4; ++i)
    for (int j = 0; j < 4; ++j) {
      int mbase = m0 + wm + i * 16 + qd * 4;
      int ncol = n0 + wn + j * 16 + fr;
      float bv2 = bias ? bias[ncol] : 0.0f;
      float* Cp = (float*)Cout;
      for (int r = 0; r < 4; ++r)
        Cp[(size_t)(mbase + r) * ldc + ncol] = acc[i][j][r] + bv2;
    }
}

// ---------------- fused attention: QK^T + mask + softmax + attn-write + PV ----------------
// grid 1024 blocks x 1024 threads (16 waves). TQ=64. Wave w: score cols
// [w*64,(w+1)*64), PV d-cols [w*32,(w+1)*32). Q A-fragments from global (L1).
// Phase1: Ks double-buffered 2 x (1024 rows x 32 h16, slot-swizzled) = 128 KB;
// issue-ahead staging, 1 barrier/chunk. Phase2: Pa = P fp16, 16 chunks of
// [64][72] (+8 pad) = 147,712 B. red (16 waves x 64 rows f32) at 147,712.
// XCD swizzle: all 16 q-tiles of one (b,h) on same XCD -> K/V stay in 4MB L2.
#define TQ 64
#define OFF_KS1 65536
#define PA_C64 4616                 /* h16 per 64-col chunk: 64*72+8 */
#define OFF_RED 147712              /* 16*PA_C64*2 */
#define CS_LD 536
#define SMEM_ATTN (OFF_RED + 4096)  /* 151,808 B */

__global__ __launch_bounds__(1024, 4) void k_attn(const h16* __restrict__ Q,
                                                  const h16* __restrict__ Km,
                                                  const uint32_t* __restrict__ bits,
                                                  const h16* __restrict__ Vtg,
                                                  float* __restrict__ attn,
                                                  h16* __restrict__ ctx) {
  extern __shared__ __align__(16) char smem[];
  h16* Ks0 = (h16*)smem;                // phase 1 buffer A (64 KB)
  h16* Ks1 = (h16*)(smem + OFF_KS1);    // phase 1 buffer B (64 KB)
  h16* Pa = (h16*)smem;                 // phase 2 (overwrites Ks)
  h16* Cs = (h16*)smem;                 // ctx staging (overwrites Pa)
  float* red = (float*)(smem + OFF_RED);

  const int tid = threadIdx.x, lane = tid & 63, wave = tid >> 6;
  // XCD-swizzled decode: wgid%8 -> XCD; all qt of one bh share an XCD.
  const int wgid = blockIdx.x;
  const int xcd = wgid & 7, g = wgid >> 3;     // g: 0..127
  const int qt = g & 15;
  const int bh = ((g >> 4) << 3) + xcd;        // 0..63
  const int b = bh >> 3, hh = bh & 7;
  const int q0 = qt * TQ;
  const int fr = lane & 15, qd = lane >> 4;

  const h16* Qg = Q + (size_t)(b * SEQ + q0) * HD + hh * DEP;
  const h16* Kg = Km + (size_t)(b * SEQ) * HD + hh * DEP;

  f32x4 acc[4][4];
  for (int i = 0; i < 4; ++i)
    for (int j = 0; j < 4; ++j) acc[i][j] = (f32x4)0.0f;

  // stage K rows [wave*64, +64) x depth [kc,kc+32) into Kb, slot-rotation swizzled
#define STAGE_K(Kb, kc)                                                      \
  do {                                                                       \
    for (int c = 0; c < 4; ++c) {                                            \
      int nbase = wave * 64 + c * 16;                                        \
      int n = nbase + (lane >> 2);                                           \
      int s = lane & 3;                                                      \
      int sp = (s - (n >> 1)) & 3;                                           \
      gload_lds16(Kg + (size_t)n * HD + (kc) + sp * 8, (Kb) + nbase * 32);   \
    }                                                                        \
  } while (0)

  STAGE_K(Ks0, 0);
  int cur = 0;
  for (int kc = 0; kc < 512; kc += 32) {
    __syncthreads();  // buf[cur] staged (vmcnt drained); prev reads of buf[cur^1] done
    if (kc + 32 < 512) STAGE_K(cur ? Ks0 : Ks1, kc + 32);  // issue-ahead
    h16x8 af[4];
#pragma unroll
    for (int i = 0; i < 4; ++i)
      af[i] = *(const h16x8*)(Qg + (size_t)(i * 16 + fr) * HD + kc + qd * 8);
    const h16* Kb = cur ? Ks1 : Ks0;
#pragma unroll
    for (int j = 0; j < 4; ++j) {
      int n = wave * 64 + j * 16 + fr;
      int slot = (qd + (n >> 1)) & 3;
      h16x8 bf = *(const h16x8*)(Kb + n * 32 + slot * 8);
      for (int i = 0; i < 4; ++i) acc[i][j] = MFMA16(af[i], bf, acc[i][j]);
    }
    cur ^= 1;
  }

  // ---- phase 1b: mask (bits) + softmax ----
  const float scale = 0.044194173824159216f;  // 1/sqrt(512)
  const uint32_t* bitp = bits + (size_t)(b * SEQ + q0) * 32 + wave * 2;
  float rmax[4][4];
#pragma unroll
  for (int i = 0; i < 4; ++i) {
    uint2 mwi[4];
    for (int r = 0; r < 4; ++r)
      mwi[r] = *(const uint2*)(bitp + (size_t)(i * 16 + qd * 4 + r) * 32);
    for (int r = 0; r < 4; ++r) rmax[i][r] = -3.4e38f;
#pragma unroll
    for (int j = 0; j < 4; ++j)
      for (int r = 0; r < 4; ++r) {
        uint32_t ww = (j >> 1) == 0 ? mwi[r].x : mwi[r].y;
        uint32_t m = (ww >> (fr + ((j & 1) << 4))) & 1u;
        float v = acc[i][j][r] * scale + (m ? -1e9f : 0.0f);
        acc[i][j][r] = v;
        rmax[i][r] = fmaxf(rmax[i][r], v);
      }
  }
  for (int i = 0; i < 4; ++i)
    for (int r = 0; r < 4; ++r)
      for (int off = 1; off < 16; off <<= 1)
        rmax[i][r] = fmaxf(rmax[i][r], __shfl_xor(rmax[i][r], off, 64));
  __syncthreads();  // all Ks reads done (protects later Pa overwrite too)
  if (fr == 0)
    for (int i = 0; i < 4; ++i)
      for (int r = 0; r < 4; ++r) red[wave * TQ + i * 16 + qd * 4 + r] = rmax[i][r];
  __syncthreads();
  float gmax[4][4];
  for (int i = 0; i < 4; ++i)
    for (int r = 0; r < 4; ++r) {
      int lr = i * 16 + qd * 4 + r;
      float m = red[lr];
      for (int w = 1; w < 16; ++w) m = fmaxf(m, red[w * TQ + lr]);
      gmax[i][r] = m;
    }
  __syncthreads();

  float rsum[4][4];
  for (int i = 0; i < 4; ++i)
    for (int r = 0; r < 4; ++r) rsum[i][r] = 0.f;
  for (int i = 0; i < 4; ++i)
    for (int j = 0; j < 4; ++j)
      for (int r = 0; r < 4; ++r) {
        float e = __expf(acc[i][j][r] - gmax[i][r]);
        acc[i][j][r] = e;
        rsum[i][r] += e;
      }
  for (int i = 0; i < 4; ++i)
    for (int r = 0; r < 4; ++r)
      for (int off = 1; off < 16; off <<= 1)
        rsum[i][r] += __shfl_xor(rsum[i][r], off, 64);
  if (fr == 0)
    for (int i = 0; i < 4; ++i)
      for (int r = 0; r < 4; ++r) red[wave * TQ + i * 16 + qd * 4 + r] = rsum[i][r];
  __syncthreads();

  // ---- phase 2a: normalize -> fp16 -> Pa (A-operand layout, 64-col chunks) ----
  // Pa element (row lr, col) at: (col>>6)*PA_C64 + lr*72 + (col&63); wave owns chunk 'wave'
  for (int i = 0; i < 4; ++i)
    for (int r = 0; r < 4; ++r) {
      int lr = i * 16 + qd * 4 + r;
      float tot = 0.f;
      for (int w = 0; w < 16; ++w) tot += red[w * TQ + lr];
      float inv = 1.0f / tot;
#pragma unroll
      for (int j = 0; j < 4; ++j)
        Pa[wave * PA_C64 + lr * 72 + j * 16 + fr] = f2h(acc[i][j][r] * inv);
    }
  __syncthreads();  // Pa complete; all waves may now read any of it

  // ---- write attn (fp32) coalesced from Pa ----
  {
    int row = tid >> 4, p = tid & 15;  // 64 rows x 16 threads
    float* ab = attn + (size_t)bh * (SEQ * (size_t)SEQ) + (size_t)(q0 + row) * SEQ;
#pragma unroll
    for (int u = 0; u < 16; ++u) {
      const h16* src = Pa + u * PA_C64 + row * 72 + p * 4;
      h16x4 hv = *(const h16x4*)src;
      float4 f = { (float)hv[0], (float)hv[1], (float)hv[2], (float)hv[3] };
      *(float4*)(ab + u * 64 + p * 4) = f;
    }
  }

  // ---- phase 2b: PV. ctx_tile[64 q x 512 d] = P[64x1024] @ V_bh; wave owns 32 d ----
  const int d0 = wave * 32;
  const h16* Vb = Vtg + (size_t)bh * (DEP * (size_t)SEQ);
  f32x4 acc2[4][2];
  for (int i = 0; i < 4; ++i)
    for (int j = 0; j < 2; ++j) acc2[i][j] = (f32x4)0.0f;

  h16x8 bfn[2];
#pragma unroll
  for (int j = 0; j < 2; ++j)
    bfn[j] = *(const h16x8*)(Vb + (size_t)(d0 + j * 16 + fr) * SEQ + qd * 8);
  for (int c2 = 0; c2 < 32; ++c2) {
    h16x8 bf[2];
#pragma unroll
    for (int j = 0; j < 2; ++j) bf[j] = bfn[j];
    if (c2 < 31) {
#pragma unroll
      for (int j = 0; j < 2; ++j)
        bfn[j] = *(const h16x8*)(Vb + (size_t)(d0 + j * 16 + fr) * SEQ + (c2 + 1) * 32 + qd * 8);
    }
    h16x8 af2[4];
#pragma unroll
    for (int i = 0; i < 4; ++i)
      af2[i] = *(const h16x8*)(Pa + (c2 >> 1) * PA_C64 + (i * 16 + fr) * 72 + (c2 & 1) * 32 + qd * 8);
    for (int i = 0; i < 4; ++i)
      for (int j = 0; j < 2; ++j) acc2[i][j] = MFMA16(af2[i], bf[j], acc2[i][j]);
  }

  // ---- ctx epilogue: regs -> Cs -> coalesced global (ctx aliases Q tile of THIS block) ----
  __syncthreads();  // all Pa reads done before Cs overwrite
  for (int i = 0; i < 4; ++i)
    for (int j = 0; j < 2; ++j)
      for (int r = 0; r < 4; ++r)
        Cs[(i * 16 + qd * 4 + r) * CS_LD + d0 + j * 16 + fr] = f2h(acc2[i][j][r]);
  __syncthreads();
  {
    int row = tid >> 4, p = tid & 15;
    h16* cg = ctx + (size_t)(b * SEQ + q0 + row) * HD + hh * DEP;
#pragma unroll
    for (int u = 0; u < 4; ++u)
      *(h16x8*)(cg + u * 128 + p * 8) = *(const h16x8*)(Cs + row * CS_LD + u * 128 + p * 8);
  }
}

extern "C" void kernel_launch(void* const* d_in, const int* in_sizes, int n_in,
                              void* d_out, int out_size, void* d_ws, size_t ws_size,
                              hipStream_t stream) {
  const float* v_ip = (const float*)d_in[0];
  const float* k_ip = (const float*)d_in[1];
  const float* q_ip = (const float*)d_in[2];
  const float* mask = (const float*)d_in[3];
  const float* wq = (const float*)d_in[4];
  const float* bq = (const float*)d_in[5];
  const float* wk = (const float*)d_in[6];
  const float* bk = (const float*)d_in[7];
  const float* wv = (const float*)d_in[8];
  const float* bv = (const float*)d_in[9];
  const float* wo = (const float*)d_in[10];
  const float* bo = (const float*)d_in[11];

  char* ws = (char*)d_ws;
  h16* Qh  = (h16*)(ws + (size_t)0);          // 64 MB; per-block overwritten by ctx
  h16* Kh  = (h16*)(ws + (size_t)67108864);   // 64 MB
  h16* Vt  = (h16*)(ws + (size_t)134217728);  // 64 MB, layout (B,H,D,S)
  h16* xq  = (h16*)(ws + (size_t)201326592);  // 8 MB each; xq reused as bits after qkv
  h16* xk  = (h16*)(ws + (size_t)209715200);
  h16* xv  = (h16*)(ws + (size_t)218103808);
  h16* WqT = (h16*)(ws + (size_t)226492416);  // 4 MB each
  h16* WkT = (h16*)(ws + (size_t)230686720);
  h16* WvT = (h16*)(ws + (size_t)234881024);
  h16* WoT = (h16*)(ws + (size_t)239075328);
  uint32_t* bits = (uint32_t*)xq;             // 1 MB (262144 words), written after qkv
  h16* ctx = Qh;

  float* out = (float*)d_out;
  float* attn = out + (size_t)BS * DEP;

  hipFuncSetAttribute((const void*)k_attn,
                      hipFuncAttributeMaxDynamicSharedMemorySize, SMEM_ATTN);

  k_conv3<<<dim3(4096, 3), 256, 0, stream>>>(q_ip, k_ip, v_ip, xq, xk, xv);
  k_transpose3<<<dim3(128, 16, 3), 256, 0, stream>>>(wq, wk, wv, WqT, WkT, WvT);
  k_transpose<<<dim3(16, 128), 256, 0, stream>>>(wo, WoT, 4096, 512);
  k_gemm_qkv<<<dim3(32, 64, 3), 256, 0, stream>>>(xq, xk, xv, WqT, WkT, WvT,
                                                  bq, bk, bv, Qh, Kh, Vt);
  // mask bits: B*S*S/32 = 262,144 words -> 1024 blocks x 256 threads
  k_maskbits<<<1024, 256, 0, stream>>>(mask, bits);
  k_attn<<<dim3(1024), 1024, SMEM_ATTN, stream>>>(Qh, Kh, bits, Vt, attn, ctx);
  k_gemm_nt<2><<<dim3(4, 64), 256, 0, stream>>>(ctx, WoT, bo, out, 8192, 512, 4096, 512);
}

// Round 3
// 1063.238 us; speedup vs baseline: 1.0738x; 1.0738x over previous
//
#include <hip/hip_runtime.h>
#include <stdint.h>
#include <stddef.h>

// Narrow MHA: B=8, S=1024, D=512 (per head), H=8.
// fp16 MFMA GEMMs (16x16x32_f16), fp32 softmax, fp32 outputs (out, attn).
// R7: back to R4 8-wave TQ=64 k_attn (best measured, 437us) with:
//  - XCD swizzle (R6-proven FETCH 558->231 MB)
//  - QK K-staging: 2x64KB LDS dbuf, counted s_waitcnt vmcnt(12) + raw s_barrier
//    (no vmcnt(0) drain in main loop); Q A-frags from global, prefetched 1 chunk ahead
//  - PV V-prefetch depth 2 (L2 latency ~200cy > 16-MFMA issue window)
typedef _Float16 h16;
typedef __attribute__((ext_vector_type(4))) _Float16 h16x4;
typedef __attribute__((ext_vector_type(8))) _Float16 h16x8;
typedef __attribute__((ext_vector_type(4))) float f32x4;

#define MFMA16(a, b, c) __builtin_amdgcn_mfma_f32_16x16x32_f16((a), (b), (c), 0, 0, 0)

#define NB 8
#define SEQ 1024
#define DEP 512
#define NH 8
#define HD 4096  /* NH*DEP */
#define BS 8192  /* NB*SEQ */

static __device__ __forceinline__ void gload_lds16(const void* g, void* l) {
  __builtin_amdgcn_global_load_lds((__attribute__((address_space(1))) void*)(g),
                                   (__attribute__((address_space(3))) void*)(l),
                                   16, 0, 0);
}

static __device__ __forceinline__ h16 f2h(float f) { return (h16)f; }

// ---------------- fused fp32 -> fp16 for q,k,v ----------------
__global__ __launch_bounds__(256) void k_conv3(const float* __restrict__ q,
                                               const float* __restrict__ k,
                                               const float* __restrict__ v,
                                               h16* __restrict__ xq, h16* __restrict__ xk,
                                               h16* __restrict__ xv) {
  int z = blockIdx.y;
  const float* in = z == 0 ? q : (z == 1 ? k : v);
  h16* out = z == 0 ? xq : (z == 1 ? xk : xv);
  int i = blockIdx.x * 256 + threadIdx.x;
  float4 f = ((const float4*)in)[i];
  h16x4 o = { f2h(f.x), f2h(f.y), f2h(f.z), f2h(f.w) };
  ((h16x4*)out)[i] = o;
}

// ---------------- mask (0/1 fp32, B*S*S floats) -> bitmask (262144 uint32) ----------------
__global__ __launch_bounds__(256) void k_maskbits(const float* __restrict__ mask,
                                                  uint32_t* __restrict__ bits) {
  int g = blockIdx.x * 256 + threadIdx.x;  // 262,144 threads, 32 floats each
  const float4* mp = (const float4*)mask + (size_t)g * 8;
  uint32_t w = 0;
#pragma unroll
  for (int u = 0; u < 8; ++u) {
    float4 f = mp[u];
    w |= (f.x != 0.f ? 1u : 0u) << (u * 4);
    w |= (f.y != 0.f ? 1u : 0u) << (u * 4 + 1);
    w |= (f.z != 0.f ? 1u : 0u) << (u * 4 + 2);
    w |= (f.w != 0.f ? 1u : 0u) << (u * 4 + 3);
  }
  bits[g] = w;
}

// ---------------- transpose + convert: in (R x C) fp32 -> out (C x R) fp16 ----------------
__global__ __launch_bounds__(256) void k_transpose(const float* __restrict__ in,
                                                   h16* __restrict__ out, int R, int C) {
  __shared__ float t[32][33];
  int c0 = blockIdx.x * 32, r0 = blockIdx.y * 32;
  int tx = threadIdx.x & 31, ty = threadIdx.x >> 5;
  for (int p = 0; p < 4; ++p)
    t[ty + p * 8][tx] = in[(size_t)(r0 + ty + p * 8) * C + c0 + tx];
  __syncthreads();
  for (int p = 0; p < 4; ++p)
    out[(size_t)(c0 + ty + p * 8) * R + r0 + tx] = f2h(t[tx][ty + p * 8]);
}

__global__ __launch_bounds__(256) void k_transpose3(const float* __restrict__ wq,
                                                    const float* __restrict__ wk,
                                                    const float* __restrict__ wv,
                                                    h16* __restrict__ oq, h16* __restrict__ ok,
                                                    h16* __restrict__ ov) {
  __shared__ float t[32][33];
  int z = blockIdx.z;
  const float* in = z == 0 ? wq : (z == 1 ? wk : wv);
  h16* out = z == 0 ? oq : (z == 1 ? ok : ov);
  const int R = 512, C = 4096;
  int c0 = blockIdx.x * 32, r0 = blockIdx.y * 32;
  int tx = threadIdx.x & 31, ty = threadIdx.x >> 5;
  for (int p = 0; p < 4; ++p)
    t[ty + p * 8][tx] = in[(size_t)(r0 + ty + p * 8) * C + c0 + tx];
  __syncthreads();
  for (int p = 0; p < 4; ++p)
    out[(size_t)(c0 + ty + p * 8) * R + r0 + tx] = f2h(t[tx][ty + p * 8]);
}

// ---------------- merged QKV projection GEMM ----------------
__global__ __launch_bounds__(256) void k_gemm_qkv(
    const h16* __restrict__ xq, const h16* __restrict__ xk, const h16* __restrict__ xv,
    const h16* __restrict__ WqT, const h16* __restrict__ WkT, const h16* __restrict__ WvT,
    const float* __restrict__ bq, const float* __restrict__ bk, const float* __restrict__ bv,
    h16* __restrict__ Qh, h16* __restrict__ Kh, h16* __restrict__ Vt) {
  __shared__ __align__(16) h16 As[128 * 64];
  __shared__ __align__(16) h16 Bs[128 * 64];
  const int z = blockIdx.z;
  const h16* A = z == 0 ? xq : (z == 1 ? xk : xv);
  const h16* Bm = z == 0 ? WqT : (z == 1 ? WkT : WvT);
  const float* bias = z == 0 ? bq : (z == 1 ? bk : bv);
  const int K = 512;
  const int tid = threadIdx.x, lane = tid & 63, wave = tid >> 6;
  const int wm = (wave >> 1) * 64, wn = (wave & 1) * 64;
  const int m0 = blockIdx.y * 128;
  const int n0 = blockIdx.x * 128;

  f32x4 acc[4][4];
  for (int i = 0; i < 4; ++i)
    for (int j = 0; j < 4; ++j) acc[i][j] = (f32x4)0.0f;

  const int lrow = lane >> 3, lcol = (lane & 7) * 8;
  const int fr = lane & 15, qd = lane >> 4;

  for (int k0 = 0; k0 < K; k0 += 64) {
    __syncthreads();
    for (int i = 0; i < 4; ++i) {
      int g = wave * 4 + i;
      int row = g * 8 + lrow;
      gload_lds16(A + (size_t)(m0 + row) * K + k0 + lcol, As + g * 512);
      gload_lds16(Bm + (size_t)(n0 + row) * K + k0 + lcol, Bs + g * 512);
    }
    __syncthreads();
    for (int kk = 0; kk < 64; kk += 32) {
      h16x8 af[4], bf[4];
      for (int i = 0; i < 4; ++i)
        af[i] = *(const h16x8*)(As + (wm + i * 16 + fr) * 64 + kk + qd * 8);
      for (int j = 0; j < 4; ++j)
        bf[j] = *(const h16x8*)(Bs + (wn + j * 16 + fr) * 64 + kk + qd * 8);
      for (int i = 0; i < 4; ++i)
        for (int j = 0; j < 4; ++j) acc[i][j] = MFMA16(af[i], bf[j], acc[i][j]);
    }
  }

  h16* Cnat = z == 0 ? Qh : Kh;
  for (int i = 0; i < 4; ++i)
    for (int j = 0; j < 4; ++j) {
      int mbase = m0 + wm + i * 16 + qd * 4;
      int ncol = n0 + wn + j * 16 + fr;
      float bv2 = bias[ncol];
      if (z < 2) {
        for (int r = 0; r < 4; ++r)
          Cnat[(size_t)(mbase + r) * HD + ncol] = f2h(acc[i][j][r] + bv2);
      } else {
        int bb = mbase >> 10, ss = mbase & 1023;
        int hh = ncol >> 9, dd = ncol & 511;
        size_t addr = ((size_t)((bb * NH + hh) * DEP + dd)) * SEQ + ss;
        h16x4 pk = { f2h(acc[i][j][0] + bv2), f2h(acc[i][j][1] + bv2),
                     f2h(acc[i][j][2] + bv2), f2h(acc[i][j][3] + bv2) };
        *(h16x4*)(Vt + addr) = pk;
      }
    }
}

// ---------------- NT GEMM (out-projection): fp32 out ----------------
template <int OUT_MODE>
__global__ __launch_bounds__(256) void k_gemm_nt(const h16* __restrict__ A,
                                                 const h16* __restrict__ Bm,
                                                 const float* __restrict__ bias,
                                                 void* __restrict__ Cout,
                                                 int M, int N, int K, int ldc) {
  __shared__ __align__(16) h16 As[128 * 64];
  __shared__ __align__(16) h16 Bs[128 * 64];
  const int tid = threadIdx.x, lane = tid & 63, wave = tid >> 6;
  const int wm = (wave >> 1) * 64, wn = (wave & 1) * 64;
  const int m0 = blockIdx.y * 128;
  const int n0 = blockIdx.x * 128;

  f32x4 acc[4][4];
  for (int i = 0; i < 4; ++i)
    for (int j = 0; j < 4; ++j) acc[i][j] = (f32x4)0.0f;

  const int lrow = lane >> 3, lcol = (lane & 7) * 8;
  const int fr = lane & 15, qd = lane >> 4;

  for (int k0 = 0; k0 < K; k0 += 64) {
    __syncthreads();
    for (int i = 0; i < 4; ++i) {
      int g = wave * 4 + i;
      int row = g * 8 + lrow;
      gload_lds16(A + (size_t)(m0 + row) * K + k0 + lcol, As + g * 512);
      gload_lds16(Bm + (size_t)(n0 + row) * K + k0 + lcol, Bs + g * 512);
    }
    __syncthreads();
    for (int kk = 0; kk < 64; kk += 32) {
      h16x8 af[4], bf[4];
      for (int i = 0; i < 4; ++i)
        af[i] = *(const h16x8*)(As + (wm + i * 16 + fr) * 64 + kk + qd * 8);
      for (int j = 0; j < 4; ++j)
        bf[j] = *(const h16x8*)(Bs + (wn + j * 16 + fr) * 64 + kk + qd * 8);
      for (int i = 0; i < 4; ++i)
        for (int j = 0; j < 4; ++j) acc[i][j] = MFMA16(af[i], bf[j], acc[i][j]);
    }
  }

  for (int i = 0; i < 4; ++i)
    for (int j = 0; j < 4; ++j) {
      int mbase = m0 + wm + i * 16 + qd * 4;
      int ncol = n0 + wn + j * 16 + fr;
      float bv2 = bias ? bias[ncol] : 0.0f;
      float* Cp = (float*)Cout;
      for (int r = 0; r < 4; ++r)
        Cp[(size_t)(mbase + r) * ldc + ncol] = acc[i][j][r] + bv2;
    }
}

// ---------------- fused attention: QK^T + mask + softmax + attn-write + PV ----------------
// grid 1024 blocks x 512 threads (8 waves). TQ=64. Wave w: score cols
// [w*128,(w+1)*128), PV d-cols [w*64,(w+1)*64).
// Phase1: Ks double-buffered 2 x (1024 rows x 32 h16, slot-swizzled) = 128 KB.
// Per chunk: issue next af (4 glb) + next stage (8 gload_lds), s_waitcnt vmcnt(12)
// (waits current chunk only), raw s_barrier, compute, raw s_barrier. No vmcnt(0)
// drain until the final chunk. Q A-frags from global, prefetched 1 chunk ahead.
// Phase2: Pa = P fp16, 16 chunks of [64][72] (+8 pad) = 147,712 B; red above.
// XCD swizzle: all 16 q-tiles of one (b,h) on same XCD -> K/V stay in 4MB L2.
#define TQ 64
#define OFF_KS1 65536
#define PA_C64 4616                 /* h16 per 64-col chunk: 64*72+8 */
#define OFF_RED 147712              /* 16*PA_C64*2 */
#define CS_LD 536
#define SMEM_ATTN (OFF_RED + 2048)  /* 149,760 B */

__global__ __launch_bounds__(512, 2) void k_attn(const h16* __restrict__ Q,
                                                 const h16* __restrict__ Km,
                                                 const uint32_t* __restrict__ bits,
                                                 const h16* __restrict__ Vtg,
                                                 float* __restrict__ attn,
                                                 h16* __restrict__ ctx) {
  extern __shared__ __align__(16) char smem[];
  h16* Ks0 = (h16*)smem;                // phase 1 buffer A (64 KB)
  h16* Ks1 = (h16*)(smem + OFF_KS1);    // phase 1 buffer B (64 KB)
  h16* Pa = (h16*)smem;                 // phase 2 (overwrites Ks)
  h16* Cs = (h16*)smem;                 // ctx staging (overwrites Pa)
  float* red = (float*)(smem + OFF_RED);

  const int tid = threadIdx.x, lane = tid & 63, wave = tid >> 6;
  // XCD-swizzled decode: wgid%8 -> XCD; all 16 qt of one bh share an XCD.
  const int wgid = blockIdx.x;
  const int xcd = wgid & 7, g = wgid >> 3;     // g: 0..127
  const int qt = g & 15;
  const int bh = ((g >> 4) << 3) + xcd;        // 0..63
  const int b = bh >> 3, hh = bh & 7;
  const int q0 = qt * TQ;
  const int fr = lane & 15, qd = lane >> 4;
  const int ncol0 = wave * 128;

  const h16* Qg = Q + (size_t)(b * SEQ + q0) * HD + hh * DEP;
  const h16* Kg = Km + (size_t)(b * SEQ) * HD + hh * DEP;

  f32x4 acc[4][8];
  for (int i = 0; i < 4; ++i)
    for (int j = 0; j < 8; ++j) acc[i][j] = (f32x4)0.0f;

  // stage K rows [wave*128, +128) x depth [kc,kc+32) into Kb, slot-rotation swizzled
#define STAGE_K(Kb, kc)                                                      \
  do {                                                                       \
    for (int c = 0; c < 8; ++c) {                                            \
      int nbase = wave * 128 + c * 16;                                       \
      int n = nbase + (lane >> 2);                                           \
      int s = lane & 3;                                                      \
      int sp = (s - (n >> 1)) & 3;                                           \
      gload_lds16(Kg + (size_t)n * HD + (kc) + sp * 8, (Kb) + nbase * 32);   \
    }                                                                        \
  } while (0)

  // prologue: af for chunk 0 (4 global loads), stage chunk 0 (8 gload_lds) -> 12 in flight
  h16x8 afc[4], afn[4];
#pragma unroll
  for (int i = 0; i < 4; ++i)
    afc[i] = *(const h16x8*)(Qg + (size_t)(i * 16 + fr) * HD + qd * 8);
  STAGE_K(Ks0, 0);

  int cur = 0;
  for (int kc = 0; kc < 512; kc += 32) {
    if (kc + 32 < 512) {
      // issue next chunk's af (4) + stage (8): 12 new in flight
#pragma unroll
      for (int i = 0; i < 4; ++i)
        afn[i] = *(const h16x8*)(Qg + (size_t)(i * 16 + fr) * HD + (kc + 32) + qd * 8);
      STAGE_K(cur ? Ks0 : Ks1, kc + 32);
      // wait for CURRENT chunk's 12 oldest ops only; 12 stay in flight
      asm volatile("s_waitcnt vmcnt(12)" ::: "memory");
    } else {
      asm volatile("s_waitcnt vmcnt(0)" ::: "memory");
    }
    __builtin_amdgcn_s_barrier();          // all waves: cur buffer staged
    __builtin_amdgcn_sched_barrier(0);     // keep ds_reads below the barrier
    const h16* Kb = cur ? Ks1 : Ks0;
#pragma unroll
    for (int j = 0; j < 8; ++j) {
      int n = ncol0 + j * 16 + fr;
      int slot = (qd + (n >> 1)) & 3;
      h16x8 bf = *(const h16x8*)(Kb + n * 32 + slot * 8);
      for (int i = 0; i < 4; ++i) acc[i][j] = MFMA16(afc[i], bf, acc[i][j]);
    }
    __builtin_amdgcn_sched_barrier(0);     // keep ds_reads above the barrier
    __builtin_amdgcn_s_barrier();          // cur reads done before it is re-staged
#pragma unroll
    for (int i = 0; i < 4; ++i) afc[i] = afn[i];
    cur ^= 1;
  }

  // ---- phase 1b: mask (bits) + softmax ----
  const float scale = 0.044194173824159216f;  // 1/sqrt(512)
  const uint32_t* bitp = bits + (size_t)(b * SEQ + q0) * 32 + wave * 4;
  float rmax[4][4];
#pragma unroll
  for (int i = 0; i < 4; ++i) {
    uint4 mwi[4];
    for (int r = 0; r < 4; ++r)
      mwi[r] = *(const uint4*)(bitp + (size_t)(i * 16 + qd * 4 + r) * 32);
    for (int r = 0; r < 4; ++r) rmax[i][r] = -3.4e38f;
#pragma unroll
    for (int j = 0; j < 8; ++j)
      for (int r = 0; r < 4; ++r) {
        uint32_t ww = (j >> 1) == 0 ? mwi[r].x
                    : (j >> 1) == 1 ? mwi[r].y
                    : (j >> 1) == 2 ? mwi[r].z : mwi[r].w;
        uint32_t m = (ww >> (fr + ((j & 1) << 4))) & 1u;
        float v = acc[i][j][r] * scale + (m ? -1e9f : 0.0f);
        acc[i][j][r] = v;
        rmax[i][r] = fmaxf(rmax[i][r], v);
      }
  }
  for (int i = 0; i < 4; ++i)
    for (int r = 0; r < 4; ++r)
      for (int off = 1; off < 16; off <<= 1)
        rmax[i][r] = fmaxf(rmax[i][r], __shfl_xor(rmax[i][r], off, 64));
  __syncthreads();
  if (fr == 0)
    for (int i = 0; i < 4; ++i)
      for (int r = 0; r < 4; ++r) red[wave * TQ + i * 16 + qd * 4 + r] = rmax[i][r];
  __syncthreads();
  float gmax[4][4];
  for (int i = 0; i < 4; ++i)
    for (int r = 0; r < 4; ++r) {
      int lr = i * 16 + qd * 4 + r;
      float m = red[lr];
      for (int w = 1; w < 8; ++w) m = fmaxf(m, red[w * TQ + lr]);
      gmax[i][r] = m;
    }
  __syncthreads();

  float rsum[4][4];
  for (int i = 0; i < 4; ++i)
    for (int r = 0; r < 4; ++r) rsum[i][r] = 0.f;
  for (int i = 0; i < 4; ++i)
    for (int j = 0; j < 8; ++j)
      for (int r = 0; r < 4; ++r) {
        float e = __expf(acc[i][j][r] - gmax[i][r]);
        acc[i][j][r] = e;
        rsum[i][r] += e;
      }
  for (int i = 0; i < 4; ++i)
    for (int r = 0; r < 4; ++r)
      for (int off = 1; off < 16; off <<= 1)
        rsum[i][r] += __shfl_xor(rsum[i][r], off, 64);
  if (fr == 0)
    for (int i = 0; i < 4; ++i)
      for (int r = 0; r < 4; ++r) red[wave * TQ + i * 16 + qd * 4 + r] = rsum[i][r];
  __syncthreads();

  // ---- phase 2a: normalize -> fp16 -> Pa (A-operand layout, 64-col chunks) ----
  // Pa element (row lr, col) at: (col>>6)*PA_C64 + lr*72 + (col&63)
  for (int i = 0; i < 4; ++i)
    for (int r = 0; r < 4; ++r) {
      int lr = i * 16 + qd * 4 + r;
      float tot = 0.f;
      for (int w = 0; w < 8; ++w) tot += red[w * TQ + lr];
      float inv = 1.0f / tot;
#pragma unroll
      for (int j = 0; j < 8; ++j) {
        int c64 = wave * 2 + (j >> 2);
        int coff = ((j & 3) << 4) + fr;
        Pa[c64 * PA_C64 + lr * 72 + coff] = f2h(acc[i][j][r] * inv);
      }
    }
  __syncthreads();  // Pa complete; all waves may now read any of it

  // ---- write attn (fp32) coalesced from Pa ----
  {
    int row = tid >> 3, p = tid & 7;
    float* ab = attn + (size_t)bh * (SEQ * (size_t)SEQ) + (size_t)(q0 + row) * SEQ;
#pragma unroll
    for (int cc = 0; cc < 4; ++cc) {
      int c2 = p * 4 + cc;                       // 32-col chunk 0..31
      const h16* src = Pa + (c2 >> 1) * PA_C64 + row * 72 + (c2 & 1) * 32;
      float* dst = ab + c2 * 32;
#pragma unroll
      for (int u = 0; u < 4; ++u) {
        h16x8 hv = *(const h16x8*)(src + u * 8);
        float4 lo = { (float)hv[0], (float)hv[1], (float)hv[2], (float)hv[3] };
        float4 hi = { (float)hv[4], (float)hv[5], (float)hv[6], (float)hv[7] };
        *(float4*)(dst + u * 8) = lo;
        *(float4*)(dst + u * 8 + 4) = hi;
      }
    }
  }

  // ---- phase 2b: PV. ctx_tile[64 q x 512 d] = P[64x1024] @ V_bh; wave owns 64 d ----
  const int d0 = wave * 64;
  const h16* Vb = Vtg + (size_t)bh * (DEP * (size_t)SEQ);
  f32x4 acc2[4][4];
  for (int i = 0; i < 4; ++i)
    for (int j = 0; j < 4; ++j) acc2[i][j] = (f32x4)0.0f;

  // V prefetch depth 2
  h16x8 bf0[4], bf1[4];
#pragma unroll
  for (int j = 0; j < 4; ++j)
    bf0[j] = *(const h16x8*)(Vb + (size_t)(d0 + j * 16 + fr) * SEQ + qd * 8);
#pragma unroll
  for (int j = 0; j < 4; ++j)
    bf1[j] = *(const h16x8*)(Vb + (size_t)(d0 + j * 16 + fr) * SEQ + 32 + qd * 8);
  for (int c2 = 0; c2 < 32; ++c2) {
    h16x8 bfu[4];
#pragma unroll
    for (int j = 0; j < 4; ++j) bfu[j] = bf0[j];
#pragma unroll
    for (int j = 0; j < 4; ++j) bf0[j] = bf1[j];
    if (c2 + 2 < 32) {
#pragma unroll
      for (int j = 0; j < 4; ++j)
        bf1[j] = *(const h16x8*)(Vb + (size_t)(d0 + j * 16 + fr) * SEQ + (c2 + 2) * 32 + qd * 8);
    }
    h16x8 af2[4];
#pragma unroll
    for (int i = 0; i < 4; ++i)
      af2[i] = *(const h16x8*)(Pa + (c2 >> 1) * PA_C64 + (i * 16 + fr) * 72 + (c2 & 1) * 32 + qd * 8);
    for (int i = 0; i < 4; ++i)
      for (int j = 0; j < 4; ++j) acc2[i][j] = MFMA16(af2[i], bfu[j], acc2[i][j]);
  }

  // ---- ctx epilogue: regs -> Cs -> coalesced global (ctx aliases Q tile of THIS block) ----
  __syncthreads();  // all Pa reads done before Cs overwrite
  for (int i = 0; i < 4; ++i)
    for (int j = 0; j < 4; ++j)
      for (int r = 0; r < 4; ++r)
        Cs[(i * 16 + qd * 4 + r) * CS_LD + d0 + j * 16 + fr] = f2h(acc2[i][j][r]);
  __syncthreads();
  {
    int row = tid >> 3, p = tid & 7;
    h16* cg = ctx + (size_t)(b * SEQ + q0 + row) * HD + hh * DEP + p * 64;
#pragma unroll
    for (int u = 0; u < 8; ++u)
      *(h16x8*)(cg + u * 8) = *(const h16x8*)(Cs + row * CS_LD + p * 64 + u * 8);
  }
}

extern "C" void kernel_launch(void* const* d_in, const int* in_sizes, int n_in,
                              void* d_out, int out_size, void* d_ws, size_t ws_size,
                              hipStream_t stream) {
  const float* v_ip = (const float*)d_in[0];
  const float* k_ip = (const float*)d_in[1];
  const float* q_ip = (const float*)d_in[2];
  const float* mask = (const float*)d_in[3];
  const float* wq = (const float*)d_in[4];
  const float* bq = (const float*)d_in[5];
  const float* wk = (const float*)d_in[6];
  const float* bk = (const float*)d_in[7];
  const float* wv = (const float*)d_in[8];
  const float* bv = (const float*)d_in[9];
  const float* wo = (const float*)d_in[10];
  const float* bo = (const float*)d_in[11];

  char* ws = (char*)d_ws;
  h16* Qh  = (h16*)(ws + (size_t)0);          // 64 MB; per-block overwritten by ctx
  h16* Kh  = (h16*)(ws + (size_t)67108864);   // 64 MB
  h16* Vt  = (h16*)(ws + (size_t)134217728);  // 64 MB, layout (B,H,D,S)
  h16* xq  = (h16*)(ws + (size_t)201326592);  // 8 MB each; xq reused as bits after qkv
  h16* xk  = (h16*)(ws + (size_t)209715200);
  h16* xv  = (h16*)(ws + (size_t)218103808);
  h16* WqT = (h16*)(ws + (size_t)226492416);  // 4 MB each
  h16* WkT = (h16*)(ws + (size_t)230686720);
  h16* WvT = (h16*)(ws + (size_t)234881024);
  h16* WoT = (h16*)(ws + (size_t)239075328);
  uint32_t* bits = (uint32_t*)xq;             // 1 MB (262144 words), written after qkv
  h16* ctx = Qh;

  float* out = (float*)d_out;
  float* attn = out + (size_t)BS * DEP;

  hipFuncSetAttribute((const void*)k_attn,
                      hipFuncAttributeMaxDynamicSharedMemorySize, SMEM_ATTN);

  k_conv3<<<dim3(4096, 3), 256, 0, stream>>>(q_ip, k_ip, v_ip, xq, xk, xv);
  k_transpose3<<<dim3(128, 16, 3), 256, 0, stream>>>(wq, wk, wv, WqT, WkT, WvT);
  k_transpose<<<dim3(16, 128), 256, 0, stream>>>(wo, WoT, 4096, 512);
  k_gemm_qkv<<<dim3(32, 64, 3), 256, 0, stream>>>(xq, xk, xv, WqT, WkT, WvT,
                                                  bq, bk, bv, Qh, Kh, Vt);
  // mask bits: B*S*S/32 = 262,144 words -> 1024 blocks x 256 threads
  k_maskbits<<<1024, 256, 0, stream>>>(mask, bits);
  k_attn<<<dim3(1024), 512, SMEM_ATTN, stream>>>(Qh, Kh, bits, Vt, attn, ctx);
  k_gemm_nt<2><<<dim3(4, 64), 256, 0, stream>>>(ctx, WoT, bo, out, 8192, 512, 4096, 512);
}

// Round 4
// 1049.710 us; speedup vs baseline: 1.0877x; 1.0129x over previous
//
#include <hip/hip_runtime.h>
#include <stdint.h>
#include <stddef.h>

// Narrow MHA: B=8, S=1024, D=512 (per head), H=8.
// fp16 MFMA GEMMs (16x16x32_f16), fp32 softmax, fp32 outputs (out, attn).
// R8: barrier-free QK^T. K fragments loaded per-lane directly from global/L2
// (cols are wave-disjoint; LDS staging saved no traffic, only cost lockstep
// barriers). Phase 1 now has 0 barriers / 0 LDS; 8 waves slip freely and hide
// L2 latency. 6 barriers total per block (softmax red + Pa + epilogue).
// Keeps: XCD swizzle (FETCH 558->104 MB proven), Pa LDS transpose for PV,
// V-prefetch depth 2, R4 epilogues.
typedef _Float16 h16;
typedef __attribute__((ext_vector_type(4))) _Float16 h16x4;
typedef __attribute__((ext_vector_type(8))) _Float16 h16x8;
typedef __attribute__((ext_vector_type(4))) float f32x4;

#define MFMA16(a, b, c) __builtin_amdgcn_mfma_f32_16x16x32_f16((a), (b), (c), 0, 0, 0)

#define NB 8
#define SEQ 1024
#define DEP 512
#define NH 8
#define HD 4096  /* NH*DEP */
#define BS 8192  /* NB*SEQ */

static __device__ __forceinline__ void gload_lds16(const void* g, void* l) {
  __builtin_amdgcn_global_load_lds((__attribute__((address_space(1))) void*)(g),
                                   (__attribute__((address_space(3))) void*)(l),
                                   16, 0, 0);
}

static __device__ __forceinline__ h16 f2h(float f) { return (h16)f; }

// ---------------- fused fp32 -> fp16 for q,k,v ----------------
__global__ __launch_bounds__(256) void k_conv3(const float* __restrict__ q,
                                               const float* __restrict__ k,
                                               const float* __restrict__ v,
                                               h16* __restrict__ xq, h16* __restrict__ xk,
                                               h16* __restrict__ xv) {
  int z = blockIdx.y;
  const float* in = z == 0 ? q : (z == 1 ? k : v);
  h16* out = z == 0 ? xq : (z == 1 ? xk : xv);
  int i = blockIdx.x * 256 + threadIdx.x;
  float4 f = ((const float4*)in)[i];
  h16x4 o = { f2h(f.x), f2h(f.y), f2h(f.z), f2h(f.w) };
  ((h16x4*)out)[i] = o;
}

// ---------------- mask (0/1 fp32, B*S*S floats) -> bitmask (262144 uint32) ----------------
__global__ __launch_bounds__(256) void k_maskbits(const float* __restrict__ mask,
                                                  uint32_t* __restrict__ bits) {
  int g = blockIdx.x * 256 + threadIdx.x;  // 262,144 threads, 32 floats each
  const float4* mp = (const float4*)mask + (size_t)g * 8;
  uint32_t w = 0;
#pragma unroll
  for (int u = 0; u < 8; ++u) {
    float4 f = mp[u];
    w |= (f.x != 0.f ? 1u : 0u) << (u * 4);
    w |= (f.y != 0.f ? 1u : 0u) << (u * 4 + 1);
    w |= (f.z != 0.f ? 1u : 0u) << (u * 4 + 2);
    w |= (f.w != 0.f ? 1u : 0u) << (u * 4 + 3);
  }
  bits[g] = w;
}

// ---------------- transpose + convert: in (R x C) fp32 -> out (C x R) fp16 ----------------
__global__ __launch_bounds__(256) void k_transpose(const float* __restrict__ in,
                                                   h16* __restrict__ out, int R, int C) {
  __shared__ float t[32][33];
  int c0 = blockIdx.x * 32, r0 = blockIdx.y * 32;
  int tx = threadIdx.x & 31, ty = threadIdx.x >> 5;
  for (int p = 0; p < 4; ++p)
    t[ty + p * 8][tx] = in[(size_t)(r0 + ty + p * 8) * C + c0 + tx];
  __syncthreads();
  for (int p = 0; p < 4; ++p)
    out[(size_t)(c0 + ty + p * 8) * R + r0 + tx] = f2h(t[tx][ty + p * 8]);
}

__global__ __launch_bounds__(256) void k_transpose3(const float* __restrict__ wq,
                                                    const float* __restrict__ wk,
                                                    const float* __restrict__ wv,
                                                    h16* __restrict__ oq, h16* __restrict__ ok,
                                                    h16* __restrict__ ov) {
  __shared__ float t[32][33];
  int z = blockIdx.z;
  const float* in = z == 0 ? wq : (z == 1 ? wk : wv);
  h16* out = z == 0 ? oq : (z == 1 ? ok : ov);
  const int R = 512, C = 4096;
  int c0 = blockIdx.x * 32, r0 = blockIdx.y * 32;
  int tx = threadIdx.x & 31, ty = threadIdx.x >> 5;
  for (int p = 0; p < 4; ++p)
    t[ty + p * 8][tx] = in[(size_t)(r0 + ty + p * 8) * C + c0 + tx];
  __syncthreads();
  for (int p = 0; p < 4; ++p)
    out[(size_t)(c0 + ty + p * 8) * R + r0 + tx] = f2h(t[tx][ty + p * 8]);
}

// ---------------- merged QKV projection GEMM ----------------
__global__ __launch_bounds__(256) void k_gemm_qkv(
    const h16* __restrict__ xq, const h16* __restrict__ xk, const h16* __restrict__ xv,
    const h16* __restrict__ WqT, const h16* __restrict__ WkT, const h16* __restrict__ WvT,
    const float* __restrict__ bq, const float* __restrict__ bk, const float* __restrict__ bv,
    h16* __restrict__ Qh, h16* __restrict__ Kh, h16* __restrict__ Vt) {
  __shared__ __align__(16) h16 As[128 * 64];
  __shared__ __align__(16) h16 Bs[128 * 64];
  const int z = blockIdx.z;
  const h16* A = z == 0 ? xq : (z == 1 ? xk : xv);
  const h16* Bm = z == 0 ? WqT : (z == 1 ? WkT : WvT);
  const float* bias = z == 0 ? bq : (z == 1 ? bk : bv);
  const int K = 512;
  const int tid = threadIdx.x, lane = tid & 63, wave = tid >> 6;
  const int wm = (wave >> 1) * 64, wn = (wave & 1) * 64;
  const int m0 = blockIdx.y * 128;
  const int n0 = blockIdx.x * 128;

  f32x4 acc[4][4];
  for (int i = 0; i < 4; ++i)
    for (int j = 0; j < 4; ++j) acc[i][j] = (f32x4)0.0f;

  const int lrow = lane >> 3, lcol = (lane & 7) * 8;
  const int fr = lane & 15, qd = lane >> 4;

  for (int k0 = 0; k0 < K; k0 += 64) {
    __syncthreads();
    for (int i = 0; i < 4; ++i) {
      int g = wave * 4 + i;
      int row = g * 8 + lrow;
      gload_lds16(A + (size_t)(m0 + row) * K + k0 + lcol, As + g * 512);
      gload_lds16(Bm + (size_t)(n0 + row) * K + k0 + lcol, Bs + g * 512);
    }
    __syncthreads();
    for (int kk = 0; kk < 64; kk += 32) {
      h16x8 af[4], bf[4];
      for (int i = 0; i < 4; ++i)
        af[i] = *(const h16x8*)(As + (wm + i * 16 + fr) * 64 + kk + qd * 8);
      for (int j = 0; j < 4; ++j)
        bf[j] = *(const h16x8*)(Bs + (wn + j * 16 + fr) * 64 + kk + qd * 8);
      for (int i = 0; i < 4; ++i)
        for (int j = 0; j < 4; ++j) acc[i][j] = MFMA16(af[i], bf[j], acc[i][j]);
    }
  }

  h16* Cnat = z == 0 ? Qh : Kh;
  for (int i = 0; i < 4; ++i)
    for (int j = 0; j < 4; ++j) {
      int mbase = m0 + wm + i * 16 + qd * 4;
      int ncol = n0 + wn + j * 16 + fr;
      float bv2 = bias[ncol];
      if (z < 2) {
        for (int r = 0; r < 4; ++r)
          Cnat[(size_t)(mbase + r) * HD + ncol] = f2h(acc[i][j][r] + bv2);
      } else {
        int bb = mbase >> 10, ss = mbase & 1023;
        int hh = ncol >> 9, dd = ncol & 511;
        size_t addr = ((size_t)((bb * NH + hh) * DEP + dd)) * SEQ + ss;
        h16x4 pk = { f2h(acc[i][j][0] + bv2), f2h(acc[i][j][1] + bv2),
                     f2h(acc[i][j][2] + bv2), f2h(acc[i][j][3] + bv2) };
        *(h16x4*)(Vt + addr) = pk;
      }
    }
}

// ---------------- NT GEMM (out-projection): fp32 out ----------------
template <int OUT_MODE>
__global__ __launch_bounds__(256) void k_gemm_nt(const h16* __restrict__ A,
                                                 const h16* __restrict__ Bm,
                                                 const float* __restrict__ bias,
                                                 void* __restrict__ Cout,
                                                 int M, int N, int K, int ldc) {
  __shared__ __align__(16) h16 As[128 * 64];
  __shared__ __align__(16) h16 Bs[128 * 64];
  const int tid = threadIdx.x, lane = tid & 63, wave = tid >> 6;
  const int wm = (wave >> 1) * 64, wn = (wave & 1) * 64;
  const int m0 = blockIdx.y * 128;
  const int n0 = blockIdx.x * 128;

  f32x4 acc[4][4];
  for (int i = 0; i < 4; ++i)
    for (int j = 0; j < 4; ++j) acc[i][j] = (f32x4)0.0f;

  const int lrow = lane >> 3, lcol = (lane & 7) * 8;
  const int fr = lane & 15, qd = lane >> 4;

  for (int k0 = 0; k0 < K; k0 += 64) {
    __syncthreads();
    for (int i = 0; i < 4; ++i) {
      int g = wave * 4 + i;
      int row = g * 8 + lrow;
      gload_lds16(A + (size_t)(m0 + row) * K + k0 + lcol, As + g * 512);
      gload_lds16(Bm + (size_t)(n0 + row) * K + k0 + lcol, Bs + g * 512);
    }
    __syncthreads();
    for (int kk = 0; kk < 64; kk += 32) {
      h16x8 af[4], bf[4];
      for (int i = 0; i < 4; ++i)
        af[i] = *(const h16x8*)(As + (wm + i * 16 + fr) * 64 + kk + qd * 8);
      for (int j = 0; j < 4; ++j)
        bf[j] = *(const h16x8*)(Bs + (wn + j * 16 + fr) * 64 + kk + qd * 8);
      for (int i = 0; i < 4; ++i)
        for (int j = 0; j < 4; ++j) acc[i][j] = MFMA16(af[i], bf[j], acc[i][j]);
    }
  }

  for (int i = 0; i < 4; ++i)
    for (int j = 0; j < 4; ++j) {
      int mbase = m0 + wm + i * 16 + qd * 4;
      int ncol = n0 + wn + j * 16 + fr;
      float bv2 = bias ? bias[ncol] : 0.0f;
      float* Cp = (float*)Cout;
      for (int r = 0; r < 4; ++r)
        Cp[(size_t)(mbase + r) * ldc + ncol] = acc[i][j][r] + bv2;
    }
}

// ---------------- fused attention: QK^T + mask + softmax + attn-write + PV ----------------
// grid 1024 blocks x 512 threads (8 waves). TQ=64. Wave w: score cols
// [w*128,(w+1)*128), PV d-cols [w*64,(w+1)*64).
// Phase1: NO LDS, NO barriers. Per-lane K/Q fragment loads from global (L2-hot
// via XCD swizzle; 16 lanes x 64B rows = full cache lines; cols wave-disjoint
// so bytes match the old staged path). Compiler pipelines chunks (unroll 2).
// Phase2: Pa = P fp16, 16 chunks of [64][72] (+8 pad) = 147,712 B; red above.
// 6 barriers/block total.
#define TQ 64
#define PA_C64 4616                 /* h16 per 64-col chunk: 64*72+8 */
#define OFF_RED 147712              /* 16*PA_C64*2 */
#define CS_LD 536
#define SMEM_ATTN (OFF_RED + 2048)  /* 149,760 B */

__global__ __launch_bounds__(512, 2) void k_attn(const h16* __restrict__ Q,
                                                 const h16* __restrict__ Km,
                                                 const uint32_t* __restrict__ bits,
                                                 const h16* __restrict__ Vtg,
                                                 float* __restrict__ attn,
                                                 h16* __restrict__ ctx) {
  extern __shared__ __align__(16) char smem[];
  h16* Pa = (h16*)smem;                 // phase 2 P tile (A-operand layout)
  h16* Cs = (h16*)smem;                 // ctx staging (overwrites Pa)
  float* red = (float*)(smem + OFF_RED);

  const int tid = threadIdx.x, lane = tid & 63, wave = tid >> 6;
  // XCD-swizzled decode: wgid%8 -> XCD; all 16 qt of one bh share an XCD.
  const int wgid = blockIdx.x;
  const int xcd = wgid & 7, g = wgid >> 3;     // g: 0..127
  const int qt = g & 15;
  const int bh = ((g >> 4) << 3) + xcd;        // 0..63
  const int b = bh >> 3, hh = bh & 7;
  const int q0 = qt * TQ;
  const int fr = lane & 15, qd = lane >> 4;
  const int ncol0 = wave * 128;

  const h16* Qg = Q + (size_t)(b * SEQ + q0) * HD + hh * DEP;
  const h16* Kg = Km + (size_t)(b * SEQ) * HD + hh * DEP;

  // per-lane row base pointers (rows fixed across the k loop)
  const h16* Qp[4];
  const h16* Kp[8];
#pragma unroll
  for (int i = 0; i < 4; ++i)
    Qp[i] = Qg + (size_t)(i * 16 + fr) * HD + qd * 8;
#pragma unroll
  for (int j = 0; j < 8; ++j)
    Kp[j] = Kg + (size_t)(ncol0 + j * 16 + fr) * HD + qd * 8;

  f32x4 acc[4][8];
  for (int i = 0; i < 4; ++i)
    for (int j = 0; j < 8; ++j) acc[i][j] = (f32x4)0.0f;

  // ---- phase 1: QK^T, barrier-free, fully register-resident ----
#pragma unroll 2
  for (int kc = 0; kc < 512; kc += 32) {
    h16x8 af[4];
#pragma unroll
    for (int i = 0; i < 4; ++i) af[i] = *(const h16x8*)(Qp[i] + kc);
#pragma unroll
    for (int j = 0; j < 8; ++j) {
      h16x8 bf = *(const h16x8*)(Kp[j] + kc);
#pragma unroll
      for (int i = 0; i < 4; ++i) acc[i][j] = MFMA16(af[i], bf, acc[i][j]);
    }
  }

  // ---- phase 1b: mask (bits) + softmax ----
  const float scale = 0.044194173824159216f;  // 1/sqrt(512)
  const uint32_t* bitp = bits + (size_t)(b * SEQ + q0) * 32 + wave * 4;
  float rmax[4][4];
#pragma unroll
  for (int i = 0; i < 4; ++i) {
    uint4 mwi[4];
    for (int r = 0; r < 4; ++r)
      mwi[r] = *(const uint4*)(bitp + (size_t)(i * 16 + qd * 4 + r) * 32);
    for (int r = 0; r < 4; ++r) rmax[i][r] = -3.4e38f;
#pragma unroll
    for (int j = 0; j < 8; ++j)
      for (int r = 0; r < 4; ++r) {
        uint32_t ww = (j >> 1) == 0 ? mwi[r].x
                    : (j >> 1) == 1 ? mwi[r].y
                    : (j >> 1) == 2 ? mwi[r].z : mwi[r].w;
        uint32_t m = (ww >> (fr + ((j & 1) << 4))) & 1u;
        float v = acc[i][j][r] * scale + (m ? -1e9f : 0.0f);
        acc[i][j][r] = v;
        rmax[i][r] = fmaxf(rmax[i][r], v);
      }
  }
  for (int i = 0; i < 4; ++i)
    for (int r = 0; r < 4; ++r)
      for (int off = 1; off < 16; off <<= 1)
        rmax[i][r] = fmaxf(rmax[i][r], __shfl_xor(rmax[i][r], off, 64));
  if (fr == 0)
    for (int i = 0; i < 4; ++i)
      for (int r = 0; r < 4; ++r) red[wave * TQ + i * 16 + qd * 4 + r] = rmax[i][r];
  __syncthreads();
  float gmax[4][4];
  for (int i = 0; i < 4; ++i)
    for (int r = 0; r < 4; ++r) {
      int lr = i * 16 + qd * 4 + r;
      float m = red[lr];
      for (int w = 1; w < 8; ++w) m = fmaxf(m, red[w * TQ + lr]);
      gmax[i][r] = m;
    }
  __syncthreads();

  float rsum[4][4];
  for (int i = 0; i < 4; ++i)
    for (int r = 0; r < 4; ++r) rsum[i][r] = 0.f;
  for (int i = 0; i < 4; ++i)
    for (int j = 0; j < 8; ++j)
      for (int r = 0; r < 4; ++r) {
        float e = __expf(acc[i][j][r] - gmax[i][r]);
        acc[i][j][r] = e;
        rsum[i][r] += e;
      }
  for (int i = 0; i < 4; ++i)
    for (int r = 0; r < 4; ++r)
      for (int off = 1; off < 16; off <<= 1)
        rsum[i][r] += __shfl_xor(rsum[i][r], off, 64);
  if (fr == 0)
    for (int i = 0; i < 4; ++i)
      for (int r = 0; r < 4; ++r) red[wave * TQ + i * 16 + qd * 4 + r] = rsum[i][r];
  __syncthreads();

  // ---- phase 2a: normalize -> fp16 -> Pa (A-operand layout, 64-col chunks) ----
  // Pa element (row lr, col) at: (col>>6)*PA_C64 + lr*72 + (col&63)
  for (int i = 0; i < 4; ++i)
    for (int r = 0; r < 4; ++r) {
      int lr = i * 16 + qd * 4 + r;
      float tot = 0.f;
      for (int w = 0; w < 8; ++w) tot += red[w * TQ + lr];
      float inv = 1.0f / tot;
#pragma unroll
      for (int j = 0; j < 8; ++j) {
        int c64 = wave * 2 + (j >> 2);
        int coff = ((j & 3) << 4) + fr;
        Pa[c64 * PA_C64 + lr * 72 + coff] = f2h(acc[i][j][r] * inv);
      }
    }
  __syncthreads();  // Pa complete; all waves may now read any of it

  // ---- write attn (fp32) coalesced from Pa ----
  {
    int row = tid >> 3, p = tid & 7;
    float* ab = attn + (size_t)bh * (SEQ * (size_t)SEQ) + (size_t)(q0 + row) * SEQ;
#pragma unroll
    for (int cc = 0; cc < 4; ++cc) {
      int c2 = p * 4 + cc;                       // 32-col chunk 0..31
      const h16* src = Pa + (c2 >> 1) * PA_C64 + row * 72 + (c2 & 1) * 32;
      float* dst = ab + c2 * 32;
#pragma unroll
      for (int u = 0; u < 4; ++u) {
        h16x8 hv = *(const h16x8*)(src + u * 8);
        float4 lo = { (float)hv[0], (float)hv[1], (float)hv[2], (float)hv[3] };
        float4 hi = { (float)hv[4], (float)hv[5], (float)hv[6], (float)hv[7] };
        *(float4*)(dst + u * 8) = lo;
        *(float4*)(dst + u * 8 + 4) = hi;
      }
    }
  }

  // ---- phase 2b: PV. ctx_tile[64 q x 512 d] = P[64x1024] @ V_bh; wave owns 64 d ----
  const int d0 = wave * 64;
  const h16* Vb = Vtg + (size_t)bh * (DEP * (size_t)SEQ);
  const h16* Vp[4];
#pragma unroll
  for (int j = 0; j < 4; ++j)
    Vp[j] = Vb + (size_t)(d0 + j * 16 + fr) * SEQ + qd * 8;
  f32x4 acc2[4][4];
  for (int i = 0; i < 4; ++i)
    for (int j = 0; j < 4; ++j) acc2[i][j] = (f32x4)0.0f;

  // V prefetch depth 2
  h16x8 bf0[4], bf1[4];
#pragma unroll
  for (int j = 0; j < 4; ++j) bf0[j] = *(const h16x8*)(Vp[j]);
#pragma unroll
  for (int j = 0; j < 4; ++j) bf1[j] = *(const h16x8*)(Vp[j] + 32);
  for (int c2 = 0; c2 < 32; ++c2) {
    h16x8 bfu[4];
#pragma unroll
    for (int j = 0; j < 4; ++j) bfu[j] = bf0[j];
#pragma unroll
    for (int j = 0; j < 4; ++j) bf0[j] = bf1[j];
    if (c2 + 2 < 32) {
#pragma unroll
      for (int j = 0; j < 4; ++j)
        bf1[j] = *(const h16x8*)(Vp[j] + (c2 + 2) * 32);
    }
    h16x8 af2[4];
#pragma unroll
    for (int i = 0; i < 4; ++i)
      af2[i] = *(const h16x8*)(Pa + (c2 >> 1) * PA_C64 + (i * 16 + fr) * 72 + (c2 & 1) * 32 + qd * 8);
    for (int i = 0; i < 4; ++i)
      for (int j = 0; j < 4; ++j) acc2[i][j] = MFMA16(af2[i], bfu[j], acc2[i][j]);
  }

  // ---- ctx epilogue: regs -> Cs -> coalesced global (ctx aliases Q tile of THIS block) ----
  __syncthreads();  // all Pa reads done before Cs overwrite
  for (int i = 0; i < 4; ++i)
    for (int j = 0; j < 4; ++j)
      for (int r = 0; r < 4; ++r)
        Cs[(i * 16 + qd * 4 + r) * CS_LD + d0 + j * 16 + fr] = f2h(acc2[i][j][r]);
  __syncthreads();
  {
    int row = tid >> 3, p = tid & 7;
    h16* cg = ctx + (size_t)(b * SEQ + q0 + row) * HD + hh * DEP + p * 64;
#pragma unroll
    for (int u = 0; u < 8; ++u)
      *(h16x8*)(cg + u * 8) = *(const h16x8*)(Cs + row * CS_LD + p * 64 + u * 8);
  }
}

extern "C" void kernel_launch(void* const* d_in, const int* in_sizes, int n_in,
                              void* d_out, int out_size, void* d_ws, size_t ws_size,
                              hipStream_t stream) {
  const float* v_ip = (const float*)d_in[0];
  const float* k_ip = (const float*)d_in[1];
  const float* q_ip = (const float*)d_in[2];
  const float* mask = (const float*)d_in[3];
  const float* wq = (const float*)d_in[4];
  const float* bq = (const float*)d_in[5];
  const float* wk = (const float*)d_in[6];
  const float* bk = (const float*)d_in[7];
  const float* wv = (const float*)d_in[8];
  const float* bv = (const float*)d_in[9];
  const float* wo = (const float*)d_in[10];
  const float* bo = (const float*)d_in[11];

  char* ws = (char*)d_ws;
  h16* Qh  = (h16*)(ws + (size_t)0);          // 64 MB; per-block overwritten by ctx
  h16* Kh  = (h16*)(ws + (size_t)67108864);   // 64 MB
  h16* Vt  = (h16*)(ws + (size_t)134217728);  // 64 MB, layout (B,H,D,S)
  h16* xq  = (h16*)(ws + (size_t)201326592);  // 8 MB each; xq reused as bits after qkv
  h16* xk  = (h16*)(ws + (size_t)209715200);
  h16* xv  = (h16*)(ws + (size_t)218103808);
  h16* WqT = (h16*)(ws + (size_t)226492416);  // 4 MB each
  h16* WkT = (h16*)(ws + (size_t)230686720);
  h16* WvT = (h16*)(ws + (size_t)234881024);
  h16* WoT = (h16*)(ws + (size_t)239075328);
  uint32_t* bits = (uint32_t*)xq;             // 1 MB (262144 words), written after qkv
  h16* ctx = Qh;

  float* out = (float*)d_out;
  float* attn = out + (size_t)BS * DEP;

  hipFuncSetAttribute((const void*)k_attn,
                      hipFuncAttributeMaxDynamicSharedMemorySize, SMEM_ATTN);

  k_conv3<<<dim3(4096, 3), 256, 0, stream>>>(q_ip, k_ip, v_ip, xq, xk, xv);
  k_transpose3<<<dim3(128, 16, 3), 256, 0, stream>>>(wq, wk, wv, WqT, WkT, WvT);
  k_transpose<<<dim3(16, 128), 256, 0, stream>>>(wo, WoT, 4096, 512);
  k_gemm_qkv<<<dim3(32, 64, 3), 256, 0, stream>>>(xq, xk, xv, WqT, WkT, WvT,
                                                  bq, bk, bv, Qh, Kh, Vt);
  // mask bits: B*S*S/32 = 262,144 words -> 1024 blocks x 256 threads
  k_maskbits<<<1024, 256, 0, stream>>>(mask, bits);
  k_attn<<<dim3(1024), 512, SMEM_ATTN, stream>>>(Qh, Kh, bits, Vt, attn, ctx);
  k_gemm_nt<2><<<dim3(4, 64), 256, 0, stream>>>(ctx, WoT, bo, out, 8192, 512, 4096, 512);
}